// Round 13
// baseline (557.708 us; speedup 1.0000x reference)
//
#include <hip/hip_runtime.h>

#define HSZ 32
#define SEQ 1024

typedef _Float16 h2 __attribute__((ext_vector_type(2)));

__device__ __forceinline__ float fast_rcp(float v) { return __builtin_amdgcn_rcpf(v); }

__device__ __forceinline__ float sigmoidf_(float v) {
    return fast_rcp(1.0f + __expf(-v));
}
__device__ __forceinline__ float tanhf_(float v) {
    return fmaf(2.0f, sigmoidf_(2.0f * v), -1.0f);
}

// v_dot2_f32_f16: exact f16 x f16 products, fp32 accumulate (full rate)
__device__ __forceinline__ float fdot2(h2 a, h2 b, float c) {
    return __builtin_amdgcn_fdot2(a, b, c, false);
}
__device__ __forceinline__ h2 bc(float f) { return __builtin_bit_cast(h2, f); }

// sum-reduce within each 16-lane row on the VALU pipe (DPP row_ror), no DS ops.
// DPP ctrl must be an immediate -> template constant.
template <int N>
__device__ __forceinline__ float row_ror_add(float p) {
    const int t = __builtin_amdgcn_update_dpp(0, __float_as_int(p), 0x120 | N, 0xF, 0xF, true);
    return p + __int_as_float(t);
}
__device__ __forceinline__ float swz_xor16_add(float p) {
    return p + __int_as_float(__builtin_amdgcn_ds_swizzle(__float_as_int(p), 0x401F));
}

// r13 (= r12 + DPP-immediate fix): ONE batch per wave (2048 waves = 2/SIMD),
// lane u=lane&31 owns ALL FOUR gate rows of unit u (upper 32 lanes mirror
// redundantly -- no extra issue cost). Weights/h in f16 via v_dot2_f32_f16 ->
// register demand ~133 (was ~290), inside the 256-reg unified budget at
// 2 waves/SIMD: no AGPR parking. DS ops/step: 4x b128 hp read + 1x b16 h
// write + 1 swizzle = 6 (was 14). Single-wave blocks: DS in-order per wave
// -> no barriers anywhere.
__global__ __launch_bounds__(64)
__attribute__((amdgpu_waves_per_eu(2, 2)))
void lstm_attn_fused(const float* __restrict__ x,
                     const float* __restrict__ W_ih,
                     const float* __restrict__ W_hh,
                     const float* __restrict__ b_ih,
                     const float* __restrict__ b_hh,
                     const float* __restrict__ attn_w,
                     const float* __restrict__ fc1_w,
                     const float* __restrict__ fc1_b,
                     const float* __restrict__ fc2_w,
                     const float* __restrict__ fc2_b,
                     float* __restrict__ out)
{
    const int lane = threadIdx.x;        // 0..63
    const int u    = lane & 31;          // hidden unit owned by this lane
    const int b    = blockIdx.x;         // batch element

    // ---- preload weights as f16 pairs (4 gate rows per lane) ----
    h2 wI[16], wF[16], wG[16], wO[16];
#pragma unroll
    for (int j = 0; j < 16; ++j) {
        wI[j] = h2{(_Float16)W_hh[(u      ) * 32 + 2*j], (_Float16)W_hh[(u      ) * 32 + 2*j + 1]};
        wF[j] = h2{(_Float16)W_hh[(u + 32 ) * 32 + 2*j], (_Float16)W_hh[(u + 32 ) * 32 + 2*j + 1]};
        wG[j] = h2{(_Float16)W_hh[(u + 64 ) * 32 + 2*j], (_Float16)W_hh[(u + 64 ) * 32 + 2*j + 1]};
        wO[j] = h2{(_Float16)W_hh[(u + 96 ) * 32 + 2*j], (_Float16)W_hh[(u + 96 ) * 32 + 2*j + 1]};
    }
    h2 wiA[4], wiB[4];
    float bb[4];
#pragma unroll
    for (int g = 0; g < 4; ++g) {
        const int r = u + g * 32;
        wiA[g] = h2{(_Float16)W_ih[r * 3 + 0], (_Float16)W_ih[r * 3 + 1]};
        wiB[g] = h2{(_Float16)W_ih[r * 3 + 2], (_Float16)0.0f};
        bb[g]  = b_ih[r] + b_hh[r];
    }
    float aw = attn_w[u];

    // Pin loop-invariants (asm defs can't be rematerialized from memory).
#pragma unroll
    for (int j = 0; j < 16; ++j) {
        asm volatile("" : "+v"(wI[j]), "+v"(wF[j]), "+v"(wG[j]), "+v"(wO[j]));
    }
#pragma unroll
    for (int g = 0; g < 4; ++g) {
        asm volatile("" : "+v"(wiA[g]), "+v"(wiB[g]), "+v"(bb[g]));
    }
    asm volatile("" : "+v"(aw));

    // h state in f16 (union dodges TBAA between b16 writes and b128 reads)
    __shared__ union HU {
        _Float16 h16[64];
        float4   v4[8];
    } hsh;
    hsh.h16[lane] = (_Float16)0.0f;

    float c = 0.0f, h = 0.0f;
    float Pacc = 0.0f, lacc = 0.0f;      // online softmax pooling (scores bounded ~5.7)

    const float4* __restrict__ xv = (const float4*)(x + (size_t)b * SEQ * 3);

    // hp = f16 pairs of h_{t-1}; h0 = 0
    h2 hp[16];
#pragma unroll
    for (int j = 0; j < 16; ++j) hp[j] = h2{(_Float16)0.0f, (_Float16)0.0f};

    auto step = [&](float x0, float x1, float x2) {
        const h2 xp = h2{(_Float16)x0, (_Float16)x1};
        const h2 xq = h2{(_Float16)x2, (_Float16)0.0f};

        // input projection (2 dot2 per gate row)
        float aI0 = fdot2(wiA[0], xp, fdot2(wiB[0], xq, bb[0])), aI1 = 0.0f;
        float aF0 = fdot2(wiA[1], xp, fdot2(wiB[1], xq, bb[1])), aF1 = 0.0f;
        float aG0 = fdot2(wiA[2], xp, fdot2(wiB[2], xq, bb[2])), aG1 = 0.0f;
        float aO0 = fdot2(wiA[3], xp, fdot2(wiB[3], xq, bb[3])), aO1 = 0.0f;

        // recurrent matvec: two independent 8-deep dot2 chains per gate
#pragma unroll
        for (int j = 0; j < 8; ++j) {
            aI0 = fdot2(wI[j], hp[j], aI0);  aI1 = fdot2(wI[j + 8], hp[j + 8], aI1);
            aF0 = fdot2(wF[j], hp[j], aF0);  aF1 = fdot2(wF[j + 8], hp[j + 8], aF1);
            aG0 = fdot2(wG[j], hp[j], aG0);  aG1 = fdot2(wG[j + 8], hp[j + 8], aG1);
            aO0 = fdot2(wO[j], hp[j], aO0);  aO1 = fdot2(wO[j + 8], hp[j + 8], aO1);
        }

        // gates -- all lane-local (no exchange on the chain)
        const float i_ = sigmoidf_(aI0 + aI1);
        const float f_ = sigmoidf_(aF0 + aF1);
        const float g_ = tanhf_   (aG0 + aG1);
        const float o_ = sigmoidf_(aO0 + aO1);

        c = fmaf(f_, c, i_ * g_);
        h = o_ * tanhf_(c);

        hsh.h16[lane] = (_Float16)h;     // publish h_t (b16 write; slots 0..31 used)

        // prefetch h_t for the NEXT step: 4x b128, in-order DS sees the write
        {
            const float4 q0 = hsh.v4[0], q1 = hsh.v4[1], q2 = hsh.v4[2], q3 = hsh.v4[3];
            hp[0]=bc(q0.x); hp[1]=bc(q0.y); hp[2]=bc(q0.z); hp[3]=bc(q0.w);
            hp[4]=bc(q1.x); hp[5]=bc(q1.y); hp[6]=bc(q1.z); hp[7]=bc(q1.w);
            hp[8]=bc(q2.x); hp[9]=bc(q2.y); hp[10]=bc(q2.z); hp[11]=bc(q2.w);
            hp[12]=bc(q3.x); hp[13]=bc(q3.y); hp[14]=bc(q3.z); hp[15]=bc(q3.w);
        }

        // attention on h_t: reduce h*aw over 32 units -- 4 DPP adds (VALU pipe)
        // within each 16-row, then one swizzle to combine the two rows.
        float p = h * aw;
        p = row_ror_add<1>(p);
        p = row_ror_add<2>(p);
        p = row_ror_add<4>(p);
        p = row_ror_add<8>(p);
        p = swz_xor16_add(p);
        const float wgt = __expf(fmaxf(p, 0.0f));
        lacc += wgt;
        Pacc = fmaf(wgt, h, Pacc);
    };

    // x software pipeline: prefetch next 4-step group while computing current
    float4 xa = xv[0], xb = xv[1], xc = xv[2];
    for (int s0 = 0; s0 < SEQ; s0 += 4) {
        const int nfi = ((s0 + 4) < SEQ) ? (((s0 + 4) * 3) >> 2) : 0;
        const float4 na = xv[nfi], nb = xv[nfi + 1], nc = xv[nfi + 2];
        step(xa.x, xa.y, xa.z);
        step(xa.w, xb.x, xb.y);
        step(xb.z, xb.w, xc.x);
        step(xc.y, xc.z, xc.w);
        xa = na; xb = nb; xc = nc;
    }

    // ---- epilogue: pooled -> fc1(relu) -> fc2 (single-wave, no barriers) ----
    __shared__ float pool[32];
    __shared__ float h1sh[16];
    if (lane < 32) pool[lane] = Pacc * fast_rcp(lacc);

    {
        const int j = lane & 15;         // fc1 row (computed redundantly by 4 lanes)
        float acc = fc1_b[j];
#pragma unroll
        for (int k = 0; k < HSZ; ++k)
            acc = fmaf(fc1_w[j * HSZ + k], pool[k], acc);
        if (lane < 16) h1sh[j] = fmaxf(acc, 0.0f);

        if (lane < 2) {
            float acc2 = fc2_b[lane];
#pragma unroll
            for (int m = 0; m < 16; ++m)
                acc2 = fmaf(fc2_w[lane * 16 + m], h1sh[m], acc2);
            out[b * 2 + lane] = acc2;
        }
    }
}

extern "C" void kernel_launch(void* const* d_in, const int* in_sizes, int n_in,
                              void* d_out, int out_size, void* d_ws, size_t ws_size,
                              hipStream_t stream) {
    const float* x      = (const float*)d_in[0];
    const float* W_ih   = (const float*)d_in[1];
    const float* W_hh   = (const float*)d_in[2];
    const float* b_ih   = (const float*)d_in[3];
    const float* b_hh   = (const float*)d_in[4];
    const float* attn_w = (const float*)d_in[5];
    const float* fc1_w  = (const float*)d_in[6];
    const float* fc1_b  = (const float*)d_in[7];
    const float* fc2_w  = (const float*)d_in[8];
    const float* fc2_b  = (const float*)d_in[9];

    const int B = in_sizes[0] / (SEQ * 3);   // 2048

    lstm_attn_fused<<<dim3(B), dim3(64), 0, stream>>>(
        x, W_ih, W_hh, b_ih, b_hh, attn_w, fc1_w, fc1_b, fc2_w, fc2_b,
        (float*)d_out);
}

// Round 14
// 318.943 us; speedup vs baseline: 1.7486x; 1.7486x over previous
//
#include <hip/hip_runtime.h>

#define HSZ 32
#define SEQ 1024

typedef float v2f __attribute__((ext_vector_type(2)));

__device__ __forceinline__ float fast_rcp(float v) { return __builtin_amdgcn_rcpf(v); }

__device__ __forceinline__ float sigmoidf_(float v) {
    return fast_rcp(1.0f + __expf(-v));
}
__device__ __forceinline__ float tanhf_(float v) {
    return fmaf(2.0f, sigmoidf_(2.0f * v), -1.0f);
}

// sum within each 16-lane row on the VALU pipe (DPP row_ror) -- proven in r13
template <int N>
__device__ __forceinline__ float row_ror_add(float p) {
    const int t = __builtin_amdgcn_update_dpp(0, __float_as_int(p), 0x120 | N, 0xF, 0xF, true);
    return p + __int_as_float(t);
}
// raw xor-16 swizzle ISSUE (result consumed one step later -- latency hidden)
__device__ __forceinline__ float swz16(float p) {
    return __int_as_float(__builtin_amdgcn_ds_swizzle(__float_as_int(p), 0x401F));
}

// r14 = r6/r7 proven fp32 skeleton (2 batches/wave, 4 gates/lane, barrier-free)
// + the attention reduce moved off the DS-latency chain:
//   - 4 dependent ds_swizzle links -> 4 DPP row_ror adds (VALU, ~free)
//   - the one remaining xor16 swizzle is ISSUED at step end and CONSUMED after
//     the NEXT step's matvec (~160cy of independent FMAs cover its latency).
// r6-r9's ~500cy/step of swizzle-stall (5 links x ~100cy DS latency, nothing
// to fill it at 1 wave/SIMD) is the theory for why 400us was sticky.
__global__ __launch_bounds__(64)
__attribute__((amdgpu_waves_per_eu(1, 1)))
void lstm_attn_fused(const float* __restrict__ x,
                     const float* __restrict__ W_ih,
                     const float* __restrict__ W_hh,
                     const float* __restrict__ b_ih,
                     const float* __restrict__ b_hh,
                     const float* __restrict__ attn_w,
                     const float* __restrict__ fc1_w,
                     const float* __restrict__ fc1_b,
                     const float* __restrict__ fc2_w,
                     const float* __restrict__ fc2_b,
                     float* __restrict__ out)
{
    const int lane = threadIdx.x;        // 0..63
    const int half = lane >> 5;          // which batch element of this block
    const int u    = lane & 31;          // hidden unit owned by this lane
    const int bsel = blockIdx.x * 2 + half;

    // ---- preload weights: 4 gate rows per lane, v2 packed ----
    const v2f* __restrict__ Whv = (const v2f*)W_hh;      // [128][16] v2f
    v2f wI[16], wF[16], wG[16], wO[16];
#pragma unroll
    for (int k = 0; k < 16; ++k) {
        wI[k] = Whv[(u      ) * 16 + k];
        wF[k] = Whv[(u + 32 ) * 16 + k];
        wG[k] = Whv[(u + 64 ) * 16 + k];
        wO[k] = Whv[(u + 96 ) * 16 + k];
    }
    float wiI[3], wiF[3], wiG[3], wiO[3];
#pragma unroll
    for (int j = 0; j < 3; ++j) {
        wiI[j] = W_ih[(u      ) * 3 + j];
        wiF[j] = W_ih[(u + 32 ) * 3 + j];
        wiG[j] = W_ih[(u + 64 ) * 3 + j];
        wiO[j] = W_ih[(u + 96 ) * 3 + j];
    }
    float bI = b_ih[u     ] + b_hh[u     ];
    float bF = b_ih[u + 32] + b_hh[u + 32];
    float bG = b_ih[u + 64] + b_hh[u + 64];
    float bO = b_ih[u + 96] + b_hh[u + 96];
    float aw = attn_w[u];

    // Pin loop-invariants (asm defs can't be rematerialized from memory).
#pragma unroll
    for (int k = 0; k < 16; ++k) {
        asm volatile("" : "+v"(wI[k]), "+v"(wF[k]), "+v"(wG[k]), "+v"(wO[k]));
    }
#pragma unroll
    for (int j = 0; j < 3; ++j) {
        asm volatile("" : "+v"(wiI[j]), "+v"(wiF[j]), "+v"(wiG[j]), "+v"(wiO[j]));
    }
    asm volatile("" : "+v"(bI), "+v"(bF), "+v"(bG), "+v"(bO), "+v"(aw));

    // h state: [0..31]=half0, [32..63]=half1. Single-wave blocks, DS in-order
    // per wave -> no barriers anywhere (r7-proven).
    __shared__ float hbuf[64];
    hbuf[lane] = 0.0f;
    const v2f* __restrict__ hb2 = (const v2f*)hbuf + (half << 4);

    float c = 0.0f, h = 0.0f;
    float Pacc = 0.0f, lacc = 0.0f;      // online softmax pooling (scores bounded ~5.7)
    float p_prev = 0.0f, sv_prev = 0.0f; // deferred attention: row-sum + in-flight swizzle

    const float4* __restrict__ xv = (const float4*)(x + (size_t)bsel * SEQ * 3);

    // hp regs hold h_{t-1}; h0 = 0 (no LDS read needed for step 1).
    v2f hp[16];
#pragma unroll
    for (int k = 0; k < 16; ++k) { hp[k].x = 0.0f; hp[k].y = 0.0f; }

    auto step = [&](float x0, float x1, float x2, float accum) {
        // ---- matvec first: ~160cy of independent FMA issue; the in-flight
        // swizzle (issued last step) and hp reads complete underneath it ----
        v2f aI; aI.x = fmaf(wiI[0],x0, fmaf(wiI[1],x1, fmaf(wiI[2],x2, bI))); aI.y = 0.0f;
        v2f aF; aF.x = fmaf(wiF[0],x0, fmaf(wiF[1],x1, fmaf(wiF[2],x2, bF))); aF.y = 0.0f;
        v2f aG; aG.x = fmaf(wiG[0],x0, fmaf(wiG[1],x1, fmaf(wiG[2],x2, bG))); aG.y = 0.0f;
        v2f aO; aO.x = fmaf(wiO[0],x0, fmaf(wiO[1],x1, fmaf(wiO[2],x2, bO))); aO.y = 0.0f;
#pragma unroll
        for (int k = 0; k < 16; ++k) {
            aI = __builtin_elementwise_fma(wI[k], hp[k], aI);
            aF = __builtin_elementwise_fma(wF[k], hp[k], aF);
            aG = __builtin_elementwise_fma(wG[k], hp[k], aG);
            aO = __builtin_elementwise_fma(wO[k], hp[k], aO);
        }

        // ---- deferred attention finish for h_{t-1} (h reg still holds it) ----
        {
            const float pf  = p_prev + sv_prev;            // swizzle long returned
            const float wgt = accum * __expf(fmaxf(pf, 0.0f));
            lacc += wgt;
            Pacc = fmaf(wgt, h, Pacc);
        }

        // ---- gates: all lane-local ----
        const float i_ = sigmoidf_(aI.x + aI.y);
        const float f_ = sigmoidf_(aF.x + aF.y);
        const float g_ = tanhf_   (aG.x + aG.y);
        const float o_ = sigmoidf_(aO.x + aO.y);

        c = fmaf(f_, c, i_ * g_);
        h = o_ * tanhf_(c);

        hbuf[lane] = h;                  // publish h_t

        // prefetch h_t for the NEXT step (in-order DS: reads see the write)
#pragma unroll
        for (int k = 0; k < 16; ++k) hp[k] = hb2[k];

        // ---- attention row-reduce on the VALU pipe (fills DS-read wait) ----
        float p = h * aw;
        p = row_ror_add<1>(p);
        p = row_ror_add<2>(p);
        p = row_ror_add<4>(p);
        p = row_ror_add<8>(p);           // every lane in its 16-row has row sum
        sv_prev = swz16(p);              // ISSUE xor16; consumed next step
        p_prev  = p;
    };

    // x software pipeline: prefetch next 4-step group while computing current
    float4 xa = xv[0], xb = xv[1], xc = xv[2];
    for (int s0 = 0; s0 < SEQ; s0 += 4) {
        const int nfi = ((s0 + 4) < SEQ) ? (((s0 + 4) * 3) >> 2) : 0;
        const float4 na = xv[nfi], nb = xv[nfi + 1], nc = xv[nfi + 2];
        step(xa.x, xa.y, xa.z, (s0 == 0) ? 0.0f : 1.0f);   // mask phantom first finish
        step(xa.w, xb.x, xb.y, 1.0f);
        step(xb.z, xb.w, xc.x, 1.0f);
        step(xc.y, xc.z, xc.w, 1.0f);
        xa = na; xb = nb; xc = nc;
    }
    // tail: finish the last step's attention (h = h_SEQ)
    {
        const float pf  = p_prev + sv_prev;
        const float wgt = __expf(fmaxf(pf, 0.0f));
        lacc += wgt;
        Pacc = fmaf(wgt, h, Pacc);
    }

    // ---- epilogue: pooled -> fc1(relu) -> fc2, per half (no barriers) ----
    hbuf[lane] = Pacc * fast_rcp(lacc);  // pooled[u] of this half's batch

    {
        const int j = lane & 15;         // fc1 row (lanes 16..31 redundant)
        const float* __restrict__ hb = hbuf + (half << 5);
        float acc = fc1_b[j];
#pragma unroll
        for (int k = 0; k < HSZ; ++k)
            acc = fmaf(fc1_w[j * HSZ + k], hb[k], acc);
        __shared__ float h1sh[2][16];
        if ((lane & 31) < 16) h1sh[half][j] = fmaxf(acc, 0.0f);

        if ((lane & 31) < 2) {
            const int oi = lane & 31;
            float acc2 = fc2_b[oi];
#pragma unroll
            for (int m = 0; m < 16; ++m)
                acc2 = fmaf(fc2_w[oi * 16 + m], h1sh[half][m], acc2);
            out[bsel * 2 + oi] = acc2;
        }
    }
}

extern "C" void kernel_launch(void* const* d_in, const int* in_sizes, int n_in,
                              void* d_out, int out_size, void* d_ws, size_t ws_size,
                              hipStream_t stream) {
    const float* x      = (const float*)d_in[0];
    const float* W_ih   = (const float*)d_in[1];
    const float* W_hh   = (const float*)d_in[2];
    const float* b_ih   = (const float*)d_in[3];
    const float* b_hh   = (const float*)d_in[4];
    const float* attn_w = (const float*)d_in[5];
    const float* fc1_w  = (const float*)d_in[6];
    const float* fc1_b  = (const float*)d_in[7];
    const float* fc2_w  = (const float*)d_in[8];
    const float* fc2_b  = (const float*)d_in[9];

    const int B = in_sizes[0] / (SEQ * 3);   // 2048

    lstm_attn_fused<<<dim3(B / 2), dim3(64), 0, stream>>>(
        x, W_ih, W_hh, b_ih, b_hh, attn_w, fc1_w, fc1_b, fc2_w, fc2_b,
        (float*)d_out);
}